// Round 3
// baseline (10978.294 us; speedup 1.0000x reference)
//
#include <hip/hip_runtime.h>

// LightGCN: out = 0.25*(e0 + S e0 + S^2 e0 + S^3 e0), S = 10M-nnz COO, N=500k, EMB=64.
// R3: bucket-by-row>>7 (3907 buckets, 128 rows each) instead of full CSR sort.
//  - scatter writes land on 3907 L2-resident frontier lines -> full-line writebacks
//    (R2's per-row scatter had a 32MB frontier -> 636MB writeback, 800us).
//  - SpMM: one block per bucket, 32KiB LDS f32 accumulator, ds_add_f32 atomics,
//    epilogue fuses dest = scale*(e0 + accum)  (combine/finalize kernels removed).
// Horner ping-pong (Z in ws, W = d_out):
//   Z=e0; L1: W = e0 + S Z; L2: Z = e0 + S W; L3: out = 0.25*(e0 + S Z).

#define NUSERS 100000
#define NNODES 500000
#define EMB 64
#define RPB 128                                   // rows per bucket
#define NBUCKETS ((NNODES + RPB - 1) / RPB)       // 3907
#define COLBITS 19
#define CMASK ((1u << COLBITS) - 1u)

// ---------------- preprocessing ----------------

__global__ void hist_bucket(const int* __restrict__ rows, int nnz,
                            int* __restrict__ counts) {
  __shared__ int h[NBUCKETS];
  for (int i = threadIdx.x; i < NBUCKETS; i += blockDim.x) h[i] = 0;
  __syncthreads();
  int i = blockIdx.x * blockDim.x + threadIdx.x;
  int stride = gridDim.x * blockDim.x;
  for (; i < nnz; i += stride) atomicAdd(&h[rows[i] >> 7], 1);
  __syncthreads();
  for (int j = threadIdx.x; j < NBUCKETS; j += blockDim.x)
    if (h[j]) atomicAdd(&counts[j], h[j]);
}

// Single-block exclusive scan of counts[n] (n <= 4096), 512 threads x 8.
__global__ void scan_buckets(const int* __restrict__ counts,
                             int* __restrict__ bptr, int* __restrict__ cursor,
                             int n, int nnz) {
  __shared__ int s[512];
  const int t = threadIdx.x;
  const int base = t * 8;
  int e[8];
  int tsum = 0;
#pragma unroll
  for (int j = 0; j < 8; ++j) {
    e[j] = (base + j < n) ? counts[base + j] : 0;
    tsum += e[j];
  }
  s[t] = tsum;
  __syncthreads();
  for (int off = 1; off < 512; off <<= 1) {
    int v = (t >= off) ? s[t - off] : 0;
    __syncthreads();
    s[t] += v;
    __syncthreads();
  }
  int run = s[t] - tsum;
#pragma unroll
  for (int j = 0; j < 8; ++j) {
    if (base + j < n) { bptr[base + j] = run; cursor[base + j] = run; }
    run += e[j];
  }
  if (t == 511) bptr[n] = nnz;
}

// Scatter (row,col,val) -> bucketed pairs. key = (row&127)<<19 | col.
__global__ void scatter_bucket(const int* __restrict__ rows,
                               const int* __restrict__ cols,
                               const float* __restrict__ vals, int nnz,
                               int* __restrict__ cursor,
                               uint2* __restrict__ pairs) {
  int i = blockIdx.x * blockDim.x + threadIdx.x;
  int stride = gridDim.x * blockDim.x;
  for (; i < nnz; i += stride) {
    int r = rows[i];
    unsigned key = ((unsigned)(r & (RPB - 1)) << COLBITS) | (unsigned)cols[i];
    int pos = atomicAdd(&cursor[r >> 7], 1);
    pairs[pos] = make_uint2(key, __float_as_uint(vals[i]));
  }
}

// Z = e0 (float4 streaming copy from the two split tables).
__global__ void init_Z(const float4* __restrict__ user4,
                       const float4* __restrict__ item4,
                       float4* __restrict__ Z4) {
  const int n4 = NNODES * EMB / 4;
  const int u4 = NUSERS * EMB / 4;
  int i = blockIdx.x * blockDim.x + threadIdx.x;
  if (i >= n4) return;
  Z4[i] = (i < u4) ? user4[i] : item4[i - u4];
}

// ---------------- bucket SpMM with fused epilogue ----------------
// accum[128][64] in LDS; dest[row] = scale * (e0[row] + accum[row]).
__global__ __launch_bounds__(512) void spmm_bucket(
    const int* __restrict__ bptr, const uint2* __restrict__ pairs,
    const float* __restrict__ Z, const float4* __restrict__ user4,
    const float4* __restrict__ item4, float4* __restrict__ dest4,
    float scale) {
  __shared__ float accum[RPB * EMB];  // 32 KiB
  const int b = blockIdx.x;
  const int base_row = b * RPB;
  for (int i = threadIdx.x; i < RPB * EMB; i += 512) accum[i] = 0.f;
  __syncthreads();

  const int lane = threadIdx.x & 63;
  const int wv = threadIdx.x >> 6;  // 0..7
  const int s = bptr[b];
  const int e = bptr[b + 1];

  int i = s + wv * 4;  // wave-private chunks of 4, stride 8 waves * 4
  for (; i + 3 < e; i += 32) {
    uint2 p0 = pairs[i + 0];
    uint2 p1 = pairs[i + 1];
    uint2 p2 = pairs[i + 2];
    uint2 p3 = pairs[i + 3];
    float z0 = Z[(size_t)(p0.x & CMASK) * EMB + lane];
    float z1 = Z[(size_t)(p1.x & CMASK) * EMB + lane];
    float z2 = Z[(size_t)(p2.x & CMASK) * EMB + lane];
    float z3 = Z[(size_t)(p3.x & CMASK) * EMB + lane];
    atomicAdd(&accum[(p0.x >> COLBITS) * EMB + lane], __uint_as_float(p0.y) * z0);
    atomicAdd(&accum[(p1.x >> COLBITS) * EMB + lane], __uint_as_float(p1.y) * z1);
    atomicAdd(&accum[(p2.x >> COLBITS) * EMB + lane], __uint_as_float(p2.y) * z2);
    atomicAdd(&accum[(p3.x >> COLBITS) * EMB + lane], __uint_as_float(p3.y) * z3);
  }
  for (; i < e; ++i) {  // <=3 leftover in this wave's final chunk
    uint2 p = pairs[i];
    float z = Z[(size_t)(p.x & CMASK) * EMB + lane];
    atomicAdd(&accum[(p.x >> COLBITS) * EMB + lane], __uint_as_float(p.y) * z);
  }
  __syncthreads();

  // epilogue: 2048 float4 = 128 rows x 16
  const int nf4 = RPB * EMB / 4;
  for (int k = threadIdx.x; k < nf4; k += 512) {
    int row = base_row + (k >> 4);
    if (row >= NNODES) break;  // k>>4 monotone per thread
    int sub = k & 15;
    float4 a = (row < NUSERS) ? user4[(size_t)row * 16 + sub]
                              : item4[(size_t)(row - NUSERS) * 16 + sub];
    float4 c = ((const float4*)accum)[k];
    float4 r;
    r.x = scale * (a.x + c.x);
    r.y = scale * (a.y + c.y);
    r.z = scale * (a.z + c.z);
    r.w = scale * (a.w + c.w);
    dest4[(size_t)row * 16 + sub] = r;
  }
}

// ---------------- fallback (R1 atomic path) ----------------

__global__ void spmm_atomic(const float* __restrict__ vals,
                            const int* __restrict__ rows,
                            const int* __restrict__ cols,
                            const float* __restrict__ user_emb,
                            const float* __restrict__ item_emb,
                            const float* __restrict__ prev, int nnz,
                            float* __restrict__ y) {
  const int lane = threadIdx.x & 63;
  int wave = (int)((blockIdx.x * blockDim.x + threadIdx.x) >> 6);
  const int nwaves = (int)((gridDim.x * blockDim.x) >> 6);
  for (int nz = wave; nz < nnz; nz += nwaves) {
    float v = vals[nz];
    int r = rows[nz];
    int c = cols[nz];
    float xv = (c < NUSERS) ? user_emb[(size_t)c * EMB + lane]
                            : item_emb[(size_t)(c - NUSERS) * EMB + lane];
    if (prev) xv += prev[(size_t)c * EMB + lane];
    atomicAdd(&y[(size_t)r * EMB + lane], v * xv);
  }
}

__global__ void finalize_kernel(const float4* __restrict__ user4,
                                const float4* __restrict__ item4,
                                float4* __restrict__ X4) {
  const int n4 = NNODES * EMB / 4;
  const int u4 = NUSERS * EMB / 4;
  int i = blockIdx.x * blockDim.x + threadIdx.x;
  if (i >= n4) return;
  float4 a = (i < u4) ? user4[i] : item4[i - u4];
  float4 b = X4[i];
  b.x = 0.25f * (a.x + b.x);
  b.y = 0.25f * (a.y + b.y);
  b.z = 0.25f * (a.z + b.z);
  b.w = 0.25f * (a.w + b.w);
  X4[i] = b;
}

// ---------------- launch ----------------

extern "C" void kernel_launch(void* const* d_in, const int* in_sizes, int n_in,
                              void* d_out, int out_size, void* d_ws, size_t ws_size,
                              hipStream_t stream) {
  const float* user_emb = (const float*)d_in[0];
  const float* item_emb = (const float*)d_in[1];
  const float* vals     = (const float*)d_in[2];
  const int*   rows     = (const int*)d_in[3];
  const int*   cols     = (const int*)d_in[4];
  const int nnz = in_sizes[2];
  float* W = (float*)d_out;  // 128 MB, ping-pong partner

  const float4* user4 = (const float4*)user_emb;
  const float4* item4 = (const float4*)item_emb;

  const size_t embBytes  = (size_t)NNODES * EMB * sizeof(float);  // 128 MB
  const size_t pairBytes = (size_t)nnz * sizeof(uint2);           // 80 MB
  const size_t ptrBytes  = ((size_t)(NBUCKETS + 1) * 4 + 255) & ~(size_t)255;
  const size_t curBytes  = ((size_t)NBUCKETS * 4 + 255) & ~(size_t)255;
  const size_t cntBytes  = ((size_t)NBUCKETS * 4 + 255) & ~(size_t)255;
  const size_t need = embBytes + pairBytes + ptrBytes + curBytes + cntBytes;

  dim3 blk(256);

  if (ws_size < need) {  // safety fallback: R1 atomic path (128 MB ws)
    float* Y = (float*)d_ws;
    hipMemsetAsync(W, 0, embBytes, stream);
    hipMemsetAsync(Y, 0, embBytes, stream);
    dim3 grid(4096);
    spmm_atomic<<<grid, blk, 0, stream>>>(vals, rows, cols, user_emb, item_emb, nullptr, nnz, W);
    spmm_atomic<<<grid, blk, 0, stream>>>(vals, rows, cols, user_emb, item_emb, W, nnz, Y);
    hipMemsetAsync(W, 0, embBytes, stream);
    spmm_atomic<<<grid, blk, 0, stream>>>(vals, rows, cols, user_emb, item_emb, Y, nnz, W);
    const int n4 = NNODES * EMB / 4;
    finalize_kernel<<<(n4 + 255) / 256, blk, 0, stream>>>(user4, item4, (float4*)W);
    return;
  }

  char* ws = (char*)d_ws;
  float* Z      = (float*)ws;  ws += embBytes;
  uint2* pairs  = (uint2*)ws;  ws += pairBytes;
  int*   bptr   = (int*)ws;    ws += ptrBytes;
  int*   cursor = (int*)ws;    ws += curBytes;
  int*   counts = (int*)ws;

  // --- bucket the COO ---
  hipMemsetAsync(counts, 0, (size_t)NBUCKETS * 4, stream);
  hist_bucket<<<256, blk, 0, stream>>>(rows, nnz, counts);
  scan_buckets<<<1, 512, 0, stream>>>(counts, bptr, cursor, NBUCKETS, nnz);
  scatter_bucket<<<1024, blk, 0, stream>>>(rows, cols, vals, nnz, cursor, pairs);

  // --- Z = e0 ---
  const int n4 = NNODES * EMB / 4;
  init_Z<<<(n4 + 255) / 256, blk, 0, stream>>>(user4, item4, (float4*)Z);

  // --- 3 layers, Horner ping-pong, fused epilogue ---
  spmm_bucket<<<NBUCKETS, 512, 0, stream>>>(bptr, pairs, Z, user4, item4,
                                            (float4*)W, 1.0f);  // W = e0 + S e0
  spmm_bucket<<<NBUCKETS, 512, 0, stream>>>(bptr, pairs, W, user4, item4,
                                            (float4*)Z, 1.0f);  // Z = e0 + S W
  spmm_bucket<<<NBUCKETS, 512, 0, stream>>>(bptr, pairs, Z, user4, item4,
                                            (float4*)W, 0.25f); // out
}

// Round 4
// 2572.564 us; speedup vs baseline: 4.2675x; 4.2675x over previous
//
#include <hip/hip_runtime.h>

// LightGCN: out = 0.25*(e0 + S e0 + S^2 e0 + S^3 e0), S = 10M-nnz COO, N=500k, EMB=64.
// R4: bucket scatter (3907 cursors, L2-resident write frontier — proven fast in R3)
//     + per-bucket LDS counting sort -> row-grouped pairs (in place) + rs/re per row
//     + 3x register-accumulating wave-per-row SpMM (no atomics in inner loop — R3's
//       ds_add-in-loop collapsed MLP and ran 5x slower than register acc).
// Horner ping-pong (Z in ws, W = d_out):
//   Z=e0; L1: W = e0 + S Z; L2: Z = e0 + S W; L3: out = 0.25*(e0 + S Z).

#define NUSERS 100000
#define NNODES 500000
#define EMB 64
#define RPB 128                                   // rows per bucket
#define NBUCKETS ((NNODES + RPB - 1) / RPB)       // 3907
#define COLBITS 19
#define CMASK ((1u << COLBITS) - 1u)
#define SORT_CAP 6016                             // pairs stageable in LDS (47KB); mean=2560
#define SLACK_PAIRS 131072                        // overflow region (never hit for random rows)

// ---------------- preprocessing ----------------

__global__ void hist_bucket(const int* __restrict__ rows, int nnz,
                            int* __restrict__ counts) {
  __shared__ int h[NBUCKETS];
  for (int i = threadIdx.x; i < NBUCKETS; i += blockDim.x) h[i] = 0;
  __syncthreads();
  int i = blockIdx.x * blockDim.x + threadIdx.x;
  int stride = gridDim.x * blockDim.x;
  for (; i < nnz; i += stride) atomicAdd(&h[rows[i] >> 7], 1);
  __syncthreads();
  for (int j = threadIdx.x; j < NBUCKETS; j += blockDim.x)
    if (h[j]) atomicAdd(&counts[j], h[j]);
}

// Single-block exclusive scan of counts[n] (n <= 4096), 512 threads x 8.
__global__ void scan_buckets(const int* __restrict__ counts,
                             int* __restrict__ bptr, int* __restrict__ cursor,
                             int n, int nnz) {
  __shared__ int s[512];
  const int t = threadIdx.x;
  const int base = t * 8;
  int e[8];
  int tsum = 0;
#pragma unroll
  for (int j = 0; j < 8; ++j) {
    e[j] = (base + j < n) ? counts[base + j] : 0;
    tsum += e[j];
  }
  s[t] = tsum;
  __syncthreads();
  for (int off = 1; off < 512; off <<= 1) {
    int v = (t >= off) ? s[t - off] : 0;
    __syncthreads();
    s[t] += v;
    __syncthreads();
  }
  int run = s[t] - tsum;
#pragma unroll
  for (int j = 0; j < 8; ++j) {
    if (base + j < n) { bptr[base + j] = run; cursor[base + j] = run; }
    run += e[j];
  }
  if (t == 511) bptr[n] = nnz;
}

// Scatter (row,col,val) -> bucketed pairs. key = (row&127)<<19 | col.
__global__ void scatter_bucket(const int* __restrict__ rows,
                               const int* __restrict__ cols,
                               const float* __restrict__ vals, int nnz,
                               int* __restrict__ cursor,
                               uint2* __restrict__ pairs) {
  int i = blockIdx.x * blockDim.x + threadIdx.x;
  int stride = gridDim.x * blockDim.x;
  for (; i < nnz; i += stride) {
    int r = rows[i];
    unsigned key = ((unsigned)(r & (RPB - 1)) << COLBITS) | (unsigned)cols[i];
    int pos = atomicAdd(&cursor[r >> 7], 1);
    pairs[pos] = make_uint2(key, __float_as_uint(vals[i]));
  }
}

// Per-bucket LDS counting sort: group pairs by row (in place), strip row bits,
// emit per-row [rs, re) into the pairs array. Overflow (>SORT_CAP) goes to slack.
__global__ __launch_bounds__(256) void sort_bucket(
    const int* __restrict__ bptr, uint2* __restrict__ pairs,
    int* __restrict__ rs, int* __restrict__ re,
    int* __restrict__ ovf_alloc, int nnz) {
  __shared__ int hist[RPB];
  __shared__ int start[RPB];
  __shared__ int cur[RPB];
  __shared__ int ovf_base;
  __shared__ uint2 out[SORT_CAP];  // 47 KiB
  const int b = blockIdx.x;
  const int t = threadIdx.x;
  const int s = bptr[b];
  const int n = bptr[b + 1] - s;
  const bool ovf = (n > SORT_CAP);

  if (t < RPB) hist[t] = 0;
  __syncthreads();
  for (int i = t; i < n; i += 256)
    atomicAdd(&hist[pairs[s + i].x >> COLBITS], 1);
  __syncthreads();

  // exclusive scan of hist -> start (Hillis-Steele over 128)
  if (t < RPB) start[t] = hist[t];
  __syncthreads();
  for (int off = 1; off < RPB; off <<= 1) {
    int v = 0;
    if (t < RPB && t >= off) v = start[t - off];
    __syncthreads();
    if (t < RPB) start[t] += v;
    __syncthreads();
  }
  if (t < RPB) { start[t] -= hist[t]; cur[t] = start[t]; }
  if (t == 0 && ovf) ovf_base = atomicAdd(ovf_alloc, n);
  __syncthreads();

  // scatter into staged LDS (or global slack if overflow)
  for (int i = t; i < n; i += 256) {
    uint2 p = pairs[s + i];
    int r = (int)(p.x >> COLBITS);
    int pos = atomicAdd(&cur[r], 1);
    uint2 v = make_uint2(p.x & CMASK, p.y);
    if (!ovf) out[pos] = v;
    else pairs[nnz + ovf_base + pos] = v;
  }
  __syncthreads();

  // write back in place (all reads of pairs[s..s+n) completed before this)
  if (!ovf)
    for (int i = t; i < n; i += 256) pairs[s + i] = out[i];

  // per-row segment pointers
  if (t < RPB) {
    int row = b * RPB + t;
    if (row < NNODES) {
      int base = ovf ? (nnz + ovf_base) : s;
      rs[row] = base + start[t];
      re[row] = base + start[t] + hist[t];
    }
  }
  if (b == 0 && t == 0) { /* nothing: spmm uses rs/re, no sentinel needed */ }
}

// Z = e0 (float4 streaming copy from the two split tables).
__global__ void init_Z(const float4* __restrict__ user4,
                       const float4* __restrict__ item4,
                       float4* __restrict__ Z4) {
  const int n4 = NNODES * EMB / 4;
  const int u4 = NUSERS * EMB / 4;
  int i = blockIdx.x * blockDim.x + threadIdx.x;
  if (i >= n4) return;
  Z4[i] = (i < u4) ? user4[i] : item4[i - u4];
}

// ---------------- fused SpMM: dest[r] = scale * (e0[r] + sum val*Z[col]) ----------------
// One wave per row; register accumulation; unroll 4 for MLP; no atomics.
__global__ __launch_bounds__(256) void spmm_fused(
    const int* __restrict__ rs, const int* __restrict__ re,
    const uint2* __restrict__ pairs, const float* __restrict__ Z,
    const float* __restrict__ user_emb, const float* __restrict__ item_emb,
    float* __restrict__ dest, float scale) {
  const int lane = threadIdx.x & 63;
  const int r = (int)((blockIdx.x * blockDim.x + threadIdx.x) >> 6);
  if (r >= NNODES) return;
  const int s = rs[r];
  const int e = re[r];
  float a0 = 0.f, a1 = 0.f, a2 = 0.f, a3 = 0.f;
  int i = s;
  for (; i + 3 < e; i += 4) {
    uint2 p0 = pairs[i + 0];
    uint2 p1 = pairs[i + 1];
    uint2 p2 = pairs[i + 2];
    uint2 p3 = pairs[i + 3];
    float z0 = Z[(size_t)p0.x * EMB + lane];
    float z1 = Z[(size_t)p1.x * EMB + lane];
    float z2 = Z[(size_t)p2.x * EMB + lane];
    float z3 = Z[(size_t)p3.x * EMB + lane];
    a0 += __uint_as_float(p0.y) * z0;
    a1 += __uint_as_float(p1.y) * z1;
    a2 += __uint_as_float(p2.y) * z2;
    a3 += __uint_as_float(p3.y) * z3;
  }
  for (; i < e; ++i) {
    uint2 p = pairs[i];
    a0 += __uint_as_float(p.y) * Z[(size_t)p.x * EMB + lane];
  }
  float acc = (a0 + a1) + (a2 + a3);
  float e0 = (r < NUSERS) ? user_emb[(size_t)r * EMB + lane]
                          : item_emb[(size_t)(r - NUSERS) * EMB + lane];
  dest[(size_t)r * EMB + lane] = scale * (e0 + acc);
}

// ---------------- fallback (R1 atomic path) ----------------

__global__ void spmm_atomic(const float* __restrict__ vals,
                            const int* __restrict__ rows,
                            const int* __restrict__ cols,
                            const float* __restrict__ user_emb,
                            const float* __restrict__ item_emb,
                            const float* __restrict__ prev, int nnz,
                            float* __restrict__ y) {
  const int lane = threadIdx.x & 63;
  int wave = (int)((blockIdx.x * blockDim.x + threadIdx.x) >> 6);
  const int nwaves = (int)((gridDim.x * blockDim.x) >> 6);
  for (int nz = wave; nz < nnz; nz += nwaves) {
    float v = vals[nz];
    int r = rows[nz];
    int c = cols[nz];
    float xv = (c < NUSERS) ? user_emb[(size_t)c * EMB + lane]
                            : item_emb[(size_t)(c - NUSERS) * EMB + lane];
    if (prev) xv += prev[(size_t)c * EMB + lane];
    atomicAdd(&y[(size_t)r * EMB + lane], v * xv);
  }
}

__global__ void finalize_kernel(const float4* __restrict__ user4,
                                const float4* __restrict__ item4,
                                float4* __restrict__ X4) {
  const int n4 = NNODES * EMB / 4;
  const int u4 = NUSERS * EMB / 4;
  int i = blockIdx.x * blockDim.x + threadIdx.x;
  if (i >= n4) return;
  float4 a = (i < u4) ? user4[i] : item4[i - u4];
  float4 b = X4[i];
  b.x = 0.25f * (a.x + b.x);
  b.y = 0.25f * (a.y + b.y);
  b.z = 0.25f * (a.z + b.z);
  b.w = 0.25f * (a.w + b.w);
  X4[i] = b;
}

// ---------------- launch ----------------

extern "C" void kernel_launch(void* const* d_in, const int* in_sizes, int n_in,
                              void* d_out, int out_size, void* d_ws, size_t ws_size,
                              hipStream_t stream) {
  const float* user_emb = (const float*)d_in[0];
  const float* item_emb = (const float*)d_in[1];
  const float* vals     = (const float*)d_in[2];
  const int*   rows     = (const int*)d_in[3];
  const int*   cols     = (const int*)d_in[4];
  const int nnz = in_sizes[2];
  float* W = (float*)d_out;  // ping-pong partner

  const float4* user4 = (const float4*)user_emb;
  const float4* item4 = (const float4*)item_emb;

  const size_t embBytes  = (size_t)NNODES * EMB * sizeof(float);          // 128 MB
  const size_t pairBytes = ((size_t)nnz + SLACK_PAIRS) * sizeof(uint2);   // ~81 MB
  const size_t rsBytes   = ((size_t)NNODES * 4 + 255) & ~(size_t)255;     // 2 MB
  const size_t reBytes   = rsBytes;
  const size_t ptrBytes  = ((size_t)(NBUCKETS + 1) * 4 + 255) & ~(size_t)255;
  const size_t curBytes  = ((size_t)NBUCKETS * 4 + 255) & ~(size_t)255;
  const size_t cntBytes  = ((size_t)NBUCKETS * 4 + 255) & ~(size_t)255;
  const size_t ovfBytes  = 256;
  const size_t need = embBytes + pairBytes + rsBytes + reBytes + ptrBytes +
                      curBytes + cntBytes + ovfBytes;

  dim3 blk(256);

  if (ws_size < need) {  // safety fallback: R1 atomic path (128 MB ws)
    float* Y = (float*)d_ws;
    hipMemsetAsync(W, 0, embBytes, stream);
    hipMemsetAsync(Y, 0, embBytes, stream);
    dim3 grid(4096);
    spmm_atomic<<<grid, blk, 0, stream>>>(vals, rows, cols, user_emb, item_emb, nullptr, nnz, W);
    spmm_atomic<<<grid, blk, 0, stream>>>(vals, rows, cols, user_emb, item_emb, W, nnz, Y);
    hipMemsetAsync(W, 0, embBytes, stream);
    spmm_atomic<<<grid, blk, 0, stream>>>(vals, rows, cols, user_emb, item_emb, Y, nnz, W);
    const int n4 = NNODES * EMB / 4;
    finalize_kernel<<<(n4 + 255) / 256, blk, 0, stream>>>(user4, item4, (float4*)W);
    return;
  }

  char* ws = (char*)d_ws;
  float* Z      = (float*)ws;  ws += embBytes;
  uint2* pairs  = (uint2*)ws;  ws += pairBytes;
  int*   rsArr  = (int*)ws;    ws += rsBytes;
  int*   reArr  = (int*)ws;    ws += reBytes;
  int*   bptr   = (int*)ws;    ws += ptrBytes;
  int*   cursor = (int*)ws;    ws += curBytes;
  int*   counts = (int*)ws;    ws += cntBytes;
  int*   ovf    = (int*)ws;

  // --- bucket + sort the COO ---
  hipMemsetAsync(counts, 0, (size_t)NBUCKETS * 4, stream);
  hipMemsetAsync(ovf, 0, 4, stream);
  hist_bucket<<<256, blk, 0, stream>>>(rows, nnz, counts);
  scan_buckets<<<1, 512, 0, stream>>>(counts, bptr, cursor, NBUCKETS, nnz);
  scatter_bucket<<<1024, blk, 0, stream>>>(rows, cols, vals, nnz, cursor, pairs);
  sort_bucket<<<NBUCKETS, 256, 0, stream>>>(bptr, pairs, rsArr, reArr, ovf, nnz);

  // --- Z = e0 ---
  const int n4 = NNODES * EMB / 4;
  init_Z<<<(n4 + 255) / 256, blk, 0, stream>>>(user4, item4, (float4*)Z);

  // --- 3 layers, Horner ping-pong, fused epilogue ---
  const int sgrid = (NNODES * 64) / 256;  // one wave per row
  spmm_fused<<<sgrid, blk, 0, stream>>>(rsArr, reArr, pairs, Z, user_emb, item_emb, W, 1.0f);
  spmm_fused<<<sgrid, blk, 0, stream>>>(rsArr, reArr, pairs, W, user_emb, item_emb, Z, 1.0f);
  spmm_fused<<<sgrid, blk, 0, stream>>>(rsArr, reArr, pairs, Z, user_emb, item_emb, W, 0.25f);
}